// Round 2
// baseline (662.898 us; speedup 1.0000x reference)
//
#include <hip/hip_runtime.h>
#include <hip/hip_bf16.h>
#include <stdint.h>

// Problem constants (batch==1)
#define CIN   512
#define COUT  512
#define HH    256
#define WW    256
#define NPX   (HH*WW)          // 65536
#define KTAP  9

typedef __attribute__((ext_vector_type(8))) short bf16x8;   // 8 bf16 (4 VGPRs)
typedef __attribute__((ext_vector_type(4))) float f32x4;    // MFMA C/D frag

// ---- async global->LDS, 16B per lane. LDS dest must be wave-uniform base;
// HW writes base + lane*16. Global src is per-lane. ----
__device__ __forceinline__ void gload_lds16(const void* g, void* l) {
  __builtin_amdgcn_global_load_lds(
      (const __attribute__((address_space(1))) uint32_t*)g,
      (__attribute__((address_space(3))) uint32_t*)l,
      16, 0, 0);
}

// ---------------------------------------------------------------------------
// Kernel 1: demod + weight prep.
// weights: (1, COUT, CIN, 3, 3) fp32.  Out: wprep[tap][co][cin] bf16,
// wprep[t][co][cin] = w[co][cin][kh][kw] * rsqrt(sum_sq(w[co]) + 1e-8), t=kh*3+kw
// ---------------------------------------------------------------------------
__global__ void demod_prep_kernel(const float* __restrict__ w,
                                  __hip_bfloat16* __restrict__ wprep) {
  const int co = blockIdx.x;
  const int t  = threadIdx.x;                  // 256 threads
  const float* wc = w + (size_t)co * (CIN * 9);

  float s = 0.f;
  for (int i = t; i < CIN * 9; i += 256) { float v = wc[i]; s += v * v; }
  // wave reduce (64 lanes)
  #pragma unroll
  for (int off = 32; off > 0; off >>= 1) s += __shfl_down(s, off);
  __shared__ float ps[4];
  if ((t & 63) == 0) ps[t >> 6] = s;
  __syncthreads();
  const float tot = ps[0] + ps[1] + ps[2] + ps[3];
  const float d = rsqrtf(tot + 1e-8f);

  for (int i = t; i < CIN * 9; i += 256) {
    int cin = i / 9;
    int tap = i - cin * 9;
    wprep[(size_t)tap * (COUT * CIN) + (size_t)co * CIN + cin] =
        __float2bfloat16(wc[i] * d);
  }
}

// ---------------------------------------------------------------------------
// Kernel 2: NCHW fp32 -> NHWC bf16.  hwc[h][w][cin]
// grid: 1024 blocks = 256 h  x  4 cin-chunks(128); 256 threads (t = w)
// ---------------------------------------------------------------------------
__global__ void to_hwc_kernel(const float* __restrict__ in,
                              __hip_bfloat16* __restrict__ hwc) {
  const int bid = blockIdx.x;
  const int h    = bid >> 2;
  const int cin0 = (bid & 3) * 128;
  const int t = threadIdx.x;                    // = w
  const size_t dst_px = ((size_t)h * WW + t) * CIN;

  for (int c8 = 0; c8 < 128; c8 += 8) {
    __hip_bfloat16 b[8];
    #pragma unroll
    for (int j = 0; j < 8; ++j) {
      float v = in[(size_t)(cin0 + c8 + j) * NPX + (size_t)h * WW + t];
      b[j] = __float2bfloat16(v);
    }
    *(uint4*)&hwc[dst_px + cin0 + c8] = *(const uint4*)b;   // 16B store
  }
}

// ---------------------------------------------------------------------------
// Kernel 3: conv as 9 shifted GEMMs, 128x128 tile, BK=32, MFMA 16x16x32 bf16.
// grid: 2048 blocks = 4 co-tiles x 512 px-tiles (px tile = 128 consecutive w
// in one image row).  256 threads = 4 waves in 2x2, each wave 64x64 output.
// ---------------------------------------------------------------------------
__global__ void conv_mfma_kernel(const __hip_bfloat16* __restrict__ hwc,
                                 const __hip_bfloat16* __restrict__ wprep,
                                 const __hip_bfloat16* __restrict__ zp,
                                 float* __restrict__ out) {
  __shared__ __align__(16) __hip_bfloat16 As[128 * 32];   // [co_row][k] 8KB
  __shared__ __align__(16) __hip_bfloat16 Bs[128 * 32];   // [px_row][k] 8KB

  const int t    = threadIdx.x;
  const int wave = t >> 6, lane = t & 63;
  const int kg   = lane >> 4, lr = lane & 15;
  const int wm   = wave >> 1, wn = wave & 1;

  const int bid = blockIdx.x;
  const int co0 = (bid & 3) * 128;
  const int pt  = bid >> 2;            // 0..511
  const int h   = pt >> 1;
  const int w0  = (pt & 1) * 128;

  // staging coords: each thread owns 16B = 8 bf16 of one row; 4 threads/row
  const int srow = t >> 2;             // 0..63 (row within 64-row pass)
  const int scol = (t & 3) * 8;        // bf16 col offset

  // wave-uniform LDS bases (pass0 rows 0..63, pass1 rows 64..127; linear order)
  __hip_bfloat16* Ab0 = &As[(wave * 64) * 8];
  __hip_bfloat16* Ab1 = &As[(256 + wave * 64) * 8];
  __hip_bfloat16* Bb0 = &Bs[(wave * 64) * 8];
  __hip_bfloat16* Bb1 = &Bs[(256 + wave * 64) * 8];

  f32x4 acc[4][4] = {};

  for (int tap = 0; tap < KTAP; ++tap) {
    const int dh = tap / 3 - 1, dw = tap % 3 - 1;
    const int hp = h + dh;
    if (hp < 0 || hp >= HH) continue;          // block-uniform: zero padding rows

    // A source rows (weights for this tap)
    const __hip_bfloat16* gw =
        wprep + (size_t)tap * (COUT * CIN) + (size_t)(co0 + srow) * CIN + scol;

    // B source pixels (shifted input); w-edge lanes -> zero page
    const int wc0 = w0 + dw + srow;            // pixel col, pass 0
    const int wc1 = wc0 + 64;                  // pixel col, pass 1
    const bool v0 = ((unsigned)wc0 < (unsigned)WW);
    const bool v1 = ((unsigned)wc1 < (unsigned)WW);
    const __hip_bfloat16* gb0 = hwc + ((long)hp * WW + wc0) * CIN + scol;
    const __hip_bfloat16* gb1 = hwc + ((long)hp * WW + wc1) * CIN + scol;

    for (int k0 = 0; k0 < CIN; k0 += 32) {
      __syncthreads();                          // prev iter's frag reads done
      gload_lds16(gw + k0,             Ab0);
      gload_lds16(gw + k0 + 64 * CIN,  Ab1);
      gload_lds16(v0 ? (const void*)(gb0 + k0) : (const void*)zp, Bb0);
      gload_lds16(v1 ? (const void*)(gb1 + k0) : (const void*)zp, Bb1);
      __syncthreads();                          // staging complete (vmcnt drained)

      bf16x8 af[4], bf[4];
      #pragma unroll
      for (int mi = 0; mi < 4; ++mi)
        af[mi] = *(const bf16x8*)&As[(wm * 64 + mi * 16 + lr) * 32 + kg * 8];
      #pragma unroll
      for (int ni = 0; ni < 4; ++ni)
        bf[ni] = *(const bf16x8*)&Bs[(wn * 64 + ni * 16 + lr) * 32 + kg * 8];

      #pragma unroll
      for (int mi = 0; mi < 4; ++mi)
        #pragma unroll
        for (int ni = 0; ni < 4; ++ni)
          acc[mi][ni] = __builtin_amdgcn_mfma_f32_16x16x32_bf16(
              af[mi], bf[ni], acc[mi][ni], 0, 0, 0);
    }
  }

  // epilogue: C/D layout col=lane&15, row=(lane>>4)*4+j  [m89-verified]
  const long pxbase = (long)h * WW + w0;
  #pragma unroll
  for (int mi = 0; mi < 4; ++mi) {
    const int row = co0 + wm * 64 + mi * 16 + kg * 4;
    #pragma unroll
    for (int ni = 0; ni < 4; ++ni) {
      const long col = pxbase + wn * 64 + ni * 16 + lr;
      #pragma unroll
      for (int j = 0; j < 4; ++j)
        out[(long)(row + j) * NPX + col] = acc[mi][ni][j];
    }
  }
}

// ---------------------------------------------------------------------------
extern "C" void kernel_launch(void* const* d_in, const int* in_sizes, int n_in,
                              void* d_out, int out_size, void* d_ws, size_t ws_size,
                              hipStream_t stream) {
  const float* inp = (const float*)d_in[0];    // (1,512,256,256) fp32
  const float* wts = (const float*)d_in[1];    // (1,512,512,3,3) fp32
  float* out = (float*)d_out;                  // (1,512,256,256) fp32

  // workspace layout
  char* ws = (char*)d_ws;
  __hip_bfloat16* hwc   = (__hip_bfloat16*)ws;                       // 64 MB
  __hip_bfloat16* wprep = (__hip_bfloat16*)(ws + (size_t)NPX * CIN * 2);  // 4.5 MB
  __hip_bfloat16* zp    = (__hip_bfloat16*)(ws + (size_t)NPX * CIN * 2
                                               + (size_t)KTAP * COUT * CIN * 2);

  hipMemsetAsync(zp, 0, 256, stream);          // zero page for padded lanes

  demod_prep_kernel<<<COUT, 256, 0, stream>>>(wts, wprep);
  to_hwc_kernel<<<HH * 4, 256, 0, stream>>>(inp, hwc);
  conv_mfma_kernel<<<(COUT / 128) * (NPX / 128), 256, 0, stream>>>(hwc, wprep, zp, out);
}

// Round 7
// 568.894 us; speedup vs baseline: 1.1652x; 1.1652x over previous
//
#include <hip/hip_runtime.h>
#include <hip/hip_bf16.h>
#include <stdint.h>

// Problem constants (batch==1)
#define CIN   512
#define COUT  512
#define HH    256
#define WW    256
#define NPX   (HH*WW)          // 65536
#define KTAP  9

typedef __attribute__((ext_vector_type(8))) short bf16x8;   // 8 bf16 (4 VGPRs)
typedef __attribute__((ext_vector_type(4))) float f32x4;    // MFMA C/D frag

// fp32 -> bf16 bits (round-to-nearest-even via __float2bfloat16)
__device__ __forceinline__ ushort f2bfu(float v) {
  __hip_bfloat16 b = __float2bfloat16(v);
  return *reinterpret_cast<ushort*>(&b);
}

// ---- async global->LDS, 16B per lane. LDS dest must be wave-uniform base;
// HW writes base + lane*16. Global src is per-lane. ----
__device__ __forceinline__ void gload_lds16(const void* g, void* l) {
  __builtin_amdgcn_global_load_lds(
      (const __attribute__((address_space(1))) uint32_t*)g,
      (__attribute__((address_space(3))) uint32_t*)l,
      16, 0, 0);
}

// ---------------------------------------------------------------------------
// Kernel 1: demod + weight prep.
// weights: (1, COUT, CIN, 3, 3) fp32.  Out: wprep[tap][co][cin] bf16.
// v2: writes are cin-coalesced per tap (2B stores, consecutive lanes ->
// consecutive cin); reads are contiguous 36B chunks per thread.
// ---------------------------------------------------------------------------
__global__ void demod_prep_kernel(const float* __restrict__ w,
                                  __hip_bfloat16* __restrict__ wprep) {
  const int co = blockIdx.x;
  const int t  = threadIdx.x;                  // 256 threads
  const float* wc = w + (size_t)co * (CIN * 9);

  float s = 0.f;
  for (int i = t; i < CIN * 9; i += 256) { float v = wc[i]; s += v * v; }
  #pragma unroll
  for (int off = 32; off > 0; off >>= 1) s += __shfl_down(s, off);
  __shared__ float ps[4];
  if ((t & 63) == 0) ps[t >> 6] = s;
  __syncthreads();
  const float tot = ps[0] + ps[1] + ps[2] + ps[3];
  const float d = rsqrtf(tot + 1e-8f);

  #pragma unroll
  for (int rep = 0; rep < 2; ++rep) {
    const int cin = t + rep * 256;
    float v[9];
    #pragma unroll
    for (int tap = 0; tap < 9; ++tap) v[tap] = wc[cin * 9 + tap];
    #pragma unroll
    for (int tap = 0; tap < 9; ++tap)
      wprep[(size_t)tap * (COUT * CIN) + (size_t)co * CIN + cin] =
          __float2bfloat16(v[tap] * d);
  }
}

// ---------------------------------------------------------------------------
// Kernel 2 (v2): NCHW fp32 -> NHWC bf16 via LDS tile transpose.
// Tile: 64 px x 64 cin.  grid = 256 h x 4 px-tiles x 8 cin-tiles = 8192.
// Load: coalesced 4B reads (64 consecutive px per wave), pack 4 cin -> 8B
// LDS store.  Write: 8B stores, 16 consecutive lanes cover 128B of cin.
// ---------------------------------------------------------------------------
__global__ void to_hwc_kernel(const float* __restrict__ in,
                              __hip_bfloat16* __restrict__ hwc) {
  __shared__ ushort T[64][68];                 // pad 68: 136B row stride
  const int bid = blockIdx.x;
  const int h  = bid >> 5;
  const int p0 = ((bid >> 3) & 3) * 64;
  const int c0 = (bid & 7) * 64;
  const int t  = threadIdx.x;

  // load phase: 4 iters; each thread reads 4 cin at one px, packs to 8B
  const int p  = t & 63;
  const int cg = (t >> 6) * 4;                 // wave's cin sub-offset
  const size_t px_gl = (size_t)h * WW + p0 + p;
  #pragma unroll
  for (int it = 0; it < 4; ++it) {
    const int c_rel = it * 16 + cg;
    const int c = c0 + c_rel;
    ushort4 u;
    u.x = f2bfu(in[(size_t)(c + 0) * NPX + px_gl]);
    u.y = f2bfu(in[(size_t)(c + 1) * NPX + px_gl]);
    u.z = f2bfu(in[(size_t)(c + 2) * NPX + px_gl]);
    u.w = f2bfu(in[(size_t)(c + 3) * NPX + px_gl]);
    *(ushort4*)&T[p][c_rel] = u;
  }
  __syncthreads();

  // write phase: 4 iters; thread -> (px = it*16 + t>>4, c4 = (t&15)*4)
  const int c4 = (t & 15) * 4;
  #pragma unroll
  for (int it = 0; it < 4; ++it) {
    const int px = it * 16 + (t >> 4);
    ushort4 v = *(ushort4*)&T[px][c4];
    *(ushort4*)&hwc[((size_t)h * WW + p0 + px) * CIN + c0 + c4] = v;
  }
}

// ---------------------------------------------------------------------------
// Kernel 3: conv as 9 shifted GEMMs, 128x128 tile, BK=32, MFMA 16x16x32 bf16.
// grid: 2048 blocks = 4 co-tiles x 512 px-tiles.  256 threads = 4 waves 2x2.
// v2: XCD-aware bijective swizzle (2048 % 8 == 0) so the 4 co-sibling blocks
// sharing one B panel land on the SAME XCD's L2.
// ---------------------------------------------------------------------------
__global__ void conv_mfma_kernel(const __hip_bfloat16* __restrict__ hwc,
                                 const __hip_bfloat16* __restrict__ wprep,
                                 const __hip_bfloat16* __restrict__ zp,
                                 float* __restrict__ out) {
  __shared__ __align__(16) __hip_bfloat16 As[128 * 32];   // [co_row][k] 8KB
  __shared__ __align__(16) __hip_bfloat16 Bs[128 * 32];   // [px_row][k] 8KB

  const int t    = threadIdx.x;
  const int wave = t >> 6, lane = t & 63;
  const int kg   = lane >> 4, lr = lane & 15;
  const int wm   = wave >> 1, wn = wave & 1;

  // XCD swizzle: blocks with bid%8==x (same XCD) get contiguous wg chunk
  const int bid = blockIdx.x;
  const int wg  = ((bid & 7) << 8) | (bid >> 3);   // 2048 = 8 * 256
  const int co0 = (wg & 3) * 128;
  const int pt  = wg >> 2;             // 0..511
  const int h   = pt >> 1;
  const int w0  = (pt & 1) * 128;

  // staging coords: each thread owns 16B = 8 bf16 of one row; 4 threads/row
  const int srow = t >> 2;             // 0..63 (row within 64-row pass)
  const int scol = (t & 3) * 8;        // bf16 col offset

  // wave-uniform LDS bases (pass0 rows 0..63, pass1 rows 64..127; linear)
  __hip_bfloat16* Ab0 = &As[(wave * 64) * 8];
  __hip_bfloat16* Ab1 = &As[(256 + wave * 64) * 8];
  __hip_bfloat16* Bb0 = &Bs[(wave * 64) * 8];
  __hip_bfloat16* Bb1 = &Bs[(256 + wave * 64) * 8];

  f32x4 acc[4][4] = {};

  for (int tap = 0; tap < KTAP; ++tap) {
    const int dh = tap / 3 - 1, dw = tap % 3 - 1;
    const int hp = h + dh;
    if (hp < 0 || hp >= HH) continue;          // block-uniform padding skip

    const __hip_bfloat16* gw =
        wprep + (size_t)tap * (COUT * CIN) + (size_t)(co0 + srow) * CIN + scol;

    const int wc0 = w0 + dw + srow;            // pixel col, pass 0
    const int wc1 = wc0 + 64;                  // pixel col, pass 1
    const bool v0 = ((unsigned)wc0 < (unsigned)WW);
    const bool v1 = ((unsigned)wc1 < (unsigned)WW);
    const __hip_bfloat16* gb0 = hwc + ((long)hp * WW + wc0) * CIN + scol;
    const __hip_bfloat16* gb1 = hwc + ((long)hp * WW + wc1) * CIN + scol;

    for (int k0 = 0; k0 < CIN; k0 += 32) {
      __syncthreads();                          // prev iter's frag reads done
      gload_lds16(gw + k0,             Ab0);
      gload_lds16(gw + k0 + 64 * CIN,  Ab1);
      gload_lds16(v0 ? (const void*)(gb0 + k0) : (const void*)zp, Bb0);
      gload_lds16(v1 ? (const void*)(gb1 + k0) : (const void*)zp, Bb1);
      __syncthreads();                          // staging complete

      bf16x8 af[4], bf[4];
      #pragma unroll
      for (int mi = 0; mi < 4; ++mi)
        af[mi] = *(const bf16x8*)&As[(wm * 64 + mi * 16 + lr) * 32 + kg * 8];
      #pragma unroll
      for (int ni = 0; ni < 4; ++ni)
        bf[ni] = *(const bf16x8*)&Bs[(wn * 64 + ni * 16 + lr) * 32 + kg * 8];

      #pragma unroll
      for (int mi = 0; mi < 4; ++mi)
        #pragma unroll
        for (int ni = 0; ni < 4; ++ni)
          acc[mi][ni] = __builtin_amdgcn_mfma_f32_16x16x32_bf16(
              af[mi], bf[ni], acc[mi][ni], 0, 0, 0);
    }
  }

  // epilogue: C/D layout col=lane&15, row=(lane>>4)*4+j  [m89-verified]
  const long pxbase = (long)h * WW + w0;
  #pragma unroll
  for (int mi = 0; mi < 4; ++mi) {
    const int row = co0 + wm * 64 + mi * 16 + kg * 4;
    #pragma unroll
    for (int ni = 0; ni < 4; ++ni) {
      const long col = pxbase + wn * 64 + ni * 16 + lr;
      #pragma unroll
      for (int j = 0; j < 4; ++j)
        out[(long)(row + j) * NPX + col] = acc[mi][ni][j];
    }
  }
}

// ---------------------------------------------------------------------------
extern "C" void kernel_launch(void* const* d_in, const int* in_sizes, int n_in,
                              void* d_out, int out_size, void* d_ws, size_t ws_size,
                              hipStream_t stream) {
  const float* inp = (const float*)d_in[0];    // (1,512,256,256) fp32
  const float* wts = (const float*)d_in[1];    // (1,512,512,3,3) fp32
  float* out = (float*)d_out;                  // (1,512,256,256) fp32

  char* ws = (char*)d_ws;
  __hip_bfloat16* hwc   = (__hip_bfloat16*)ws;                       // 64 MB
  __hip_bfloat16* wprep = (__hip_bfloat16*)(ws + (size_t)NPX * CIN * 2);  // 4.5 MB
  __hip_bfloat16* zp    = (__hip_bfloat16*)(ws + (size_t)NPX * CIN * 2
                                               + (size_t)KTAP * COUT * CIN * 2);

  (void)hipMemsetAsync(zp, 0, 256, stream);    // zero page for padded lanes

  demod_prep_kernel<<<COUT, 256, 0, stream>>>(wts, wprep);
  to_hwc_kernel<<<HH * 32, 256, 0, stream>>>(inp, hwc);
  conv_mfma_kernel<<<(COUT / 128) * (NPX / 128), 256, 0, stream>>>(hwc, wprep, zp, out);
}